// Round 8
// baseline (86.126 us; speedup 1.0000x reference)
//
#include <hip/hip_runtime.h>
#include <math.h>

// E8 quantizer — grid-stride + register-prefetch pipeline.
// Post-mortems baked in:
//  - r5: nontemporal 16B stores defeat L2 write-merge (31->75 MB writes). Plain stores.
//  - r6: 2-pt/thread (both in registers up front) got serialized at min-VGPR,
//        halving TLP. Here TLP stays 8 waves/SIMD (2048 blocks x 256) and the
//        NEXT point's loads are issued before the CURRENT point's compute, so
//        ~430 cyc of independent ALU covers the load latency each iteration.
//  - r7: VALU trim was invisible -> latency-bound, not issue-bound.
// Math (unchanged, passing since r2): logit = K*dot + C in exp2 units,
// K=2*log2(e)/T, C=-sqrt(2)*|x|*K; 32 exp2/pt via factored exponentials;
// positive prefix/suffix sums (no cancellation).

static constexpr float TEMP = 0.3f;

typedef float vfloat4 __attribute__((ext_vector_type(4)));

__device__ __forceinline__ float fexp2(float v) { return __builtin_amdgcn_exp2f(v); }
__device__ __forceinline__ float frcp(float v) { return __builtin_amdgcn_rcpf(v); }

__device__ __forceinline__ void e8_compute_store(
    const vfloat4 xa, const vfloat4 xb, vfloat4* __restrict__ oo, int idx)
{
    float xv[8] = {xa.x, xa.y, xa.z, xa.w, xb.x, xb.y, xb.z, xb.w};

    const float K  = 2.0f * 1.44269504088896340736f / TEMP;  // exp2 units
    const float Kh = 0.5f * K;
    float nrm2 = 0.f;
#pragma unroll
    for (int k = 0; k < 8; ++k) nrm2 = fmaf(xv[k], xv[k], nrm2);
    const float r  = sqrtf(nrm2);
    const float C  = -1.41421356237309515f * r * K;
    const float C2 = 0.5f * C;
    const float C4 = 0.25f * C;

    // ---- per-pair exponentials for half-roots (16 exps) ----
    float e01[4], e23[4], e45[4], e67[4];
    {
        const float u01 = xv[0] + xv[1], v01 = xv[1] - xv[0];
        const float u23 = xv[2] + xv[3], v23 = xv[3] - xv[2];
        const float u45 = xv[4] + xv[5], v45 = xv[5] - xv[4];
        const float u67 = xv[6] + xv[7], v67 = xv[7] - xv[6];
        e01[0] = fexp2(fmaf(u01, Kh, C4)); e01[3] = fexp2(fmaf(-u01, Kh, C4));
        e01[1] = fexp2(fmaf(v01, Kh, C4)); e01[2] = fexp2(fmaf(-v01, Kh, C4));
        e23[0] = fexp2(fmaf(u23, Kh, C4)); e23[3] = fexp2(fmaf(-u23, Kh, C4));
        e23[1] = fexp2(fmaf(v23, Kh, C4)); e23[2] = fexp2(fmaf(-v23, Kh, C4));
        e45[0] = fexp2(fmaf(u45, Kh, C4)); e45[3] = fexp2(fmaf(-u45, Kh, C4));
        e45[1] = fexp2(fmaf(v45, Kh, C4)); e45[2] = fexp2(fmaf(-v45, Kh, C4));
        e67[0] = fexp2(fmaf(u67, Kh, C4)); e67[3] = fexp2(fmaf(-u67, Kh, C4));
        e67[1] = fexp2(fmaf(v67, Kh, C4)); e67[2] = fexp2(fmaf(-v67, Kh, C4));
    }

    const float G01e = e01[0] + e01[3], G01o = e01[1] + e01[2];
    const float G23e = e23[0] + e23[3], G23o = e23[1] + e23[2];
    const float G45e = e45[0] + e45[3], G45o = e45[1] + e45[2];
    const float G67e = e67[0] + e67[3], G67o = e67[1] + e67[2];
    const float dA01 = e01[0] - e01[3], dB01 = e01[2] - e01[1];
    const float dA23 = e23[0] - e23[3], dB23 = e23[2] - e23[1];
    const float dA45 = e45[0] - e45[3], dB45 = e45[2] - e45[1];
    const float dA67 = e67[0] - e67[3], dB67 = e67[2] - e67[1];

    const float SAe = fmaf(G01e, G23e, G01o * G23o);
    const float SAo = fmaf(G01e, G23o, G01o * G23e);
    const float SBe = fmaf(G45e, G67e, G45o * G67o);
    const float SBo = fmaf(G45e, G67o, G45o * G67e);
    const float s2sum = fmaf(SAe, SBe, SAo * SBo);

    const float M01e = fmaf(G23e, SBe, G23o * SBo), M01o = fmaf(G23e, SBo, G23o * SBe);
    const float M23e = fmaf(G01e, SBe, G01o * SBo), M23o = fmaf(G01e, SBo, G01o * SBe);
    const float M45e = fmaf(G67e, SAe, G67o * SAo), M45o = fmaf(G67e, SAo, G67o * SAe);
    const float M67e = fmaf(G45e, SAe, G45o * SAo), M67o = fmaf(G45e, SAo, G45o * SAe);

    float comp[8];
    {
        const float t0 = dA01 * M01e, t1 = dB01 * M01o;
        comp[0] = t0 + t1; comp[1] = t0 - t1;
        const float t2 = dA23 * M23e, t3 = dB23 * M23o;
        comp[2] = t2 + t3; comp[3] = t2 - t3;
        const float t4 = dA45 * M45e, t5 = dB45 * M45o;
        comp[4] = t4 + t5; comp[5] = t4 - t5;
        const float t6 = dA67 * M67e, t7 = dB67 * M67o;
        comp[6] = t6 + t7; comp[7] = t6 - t7;
    }

    // ---- 112 integer roots via 16 factored exps ----
    float P[8], D[8];
#pragma unroll
    for (int i = 0; i < 8; ++i) {
        const float ep = fexp2(fmaf(xv[i],  K, C2));
        const float em = fexp2(fmaf(-xv[i], K, C2));
        P[i] = ep + em;
        D[i] = ep - em;
    }
    float suf[9];
    suf[8] = 0.f;
#pragma unroll
    for (int i = 7; i >= 0; --i) suf[i] = suf[i + 1] + P[i];
    float pre = 0.f, ssum_int = 0.f;
    float acc[8];
#pragma unroll
    for (int i = 0; i < 8; ++i) {
        const float Q = pre + suf[i + 1];             // sum_{j != i} P[j]
        acc[i] = D[i] * Q;
        ssum_int = fmaf(P[i], suf[i + 1], ssum_int);  // sum_{i<j} P_i P_j
        pre += P[i];
    }

    const float ssum = ssum_int + s2sum;
    const float inv  = frcp(ssum);
    float outv[8];
#pragma unroll
    for (int k = 0; k < 8; ++k) {
        const float total = fmaf(0.5f, comp[k], acc[k]);
        outv[k] = total * inv;  // == x + (q - x) to <=1 ulp of |x|; thr 2e-2
    }
    vfloat4 oa = {outv[0], outv[1], outv[2], outv[3]};
    vfloat4 ob = {outv[4], outv[5], outv[6], outv[7]};
    oo[idx * 2 + 0] = oa;
    oo[idx * 2 + 1] = ob;
}

__global__ __launch_bounds__(256, 8) void e8_quant_kernel(
    const float* __restrict__ x, float* __restrict__ out, int n)
{
    const int stride = gridDim.x * blockDim.x;
    int idx = blockIdx.x * blockDim.x + threadIdx.x;
    if (idx >= n) return;

    const vfloat4* __restrict__ xi = reinterpret_cast<const vfloat4*>(x);
    vfloat4* __restrict__ oo = reinterpret_cast<vfloat4*>(out);

    vfloat4 a0 = xi[idx * 2 + 0];
    vfloat4 a1 = xi[idx * 2 + 1];
    for (;;) {
        const int nxt = idx + stride;
        const bool has = nxt < n;
        vfloat4 b0, b1;
        if (has) {                       // prefetch next point BEFORE compute
            b0 = xi[nxt * 2 + 0];
            b1 = xi[nxt * 2 + 1];
        }
        e8_compute_store(a0, a1, oo, idx);  // ~430 cyc ALU covers load latency
        if (!has) break;
        a0 = b0; a1 = b1; idx = nxt;
    }
}

extern "C" void kernel_launch(void* const* d_in, const int* in_sizes, int n_in,
                              void* d_out, int out_size, void* d_ws, size_t ws_size,
                              hipStream_t stream) {
    const float* x = (const float*)d_in[0];
    float* out = (float*)d_out;
    const int n = in_sizes[0] / 8;   // points
    const int block = 256;
    int grid = 2048;                 // 8 waves/SIMD over 256 CUs
    const int max_grid = (n + block - 1) / block;
    if (grid > max_grid) grid = max_grid;
    hipLaunchKernelGGL(e8_quant_kernel, dim3(grid), dim3(block), 0, stream, x, out, n);
}